// Round 1
// baseline (2491.566 us; speedup 1.0000x reference)
//
#include <hip/hip_runtime.h>
#include <hip/hip_bf16.h>
#include <math.h>

#define B_   16
#define S_   4096
#define DIN  1024
#define H_   8
#define HD_  64
#define V_   512
#define FOUT 120

#define TM 64
#define TN 64
#define BK 16

// total constant: 0.1 * scaling^2 / S = 0.1 / (64 * 4096)
__device__ const float CSCALE = 0.1f / (64.0f * 4096.0f);
__device__ const float EPSF = 1e-5f;

// Kernel 1: fused q/k/v GEMM (shared A) + pair-swap triple product + fold.
// outacc: float[B_*V_] = float[8192], pre-zeroed, accumulated via atomicAdd.
__global__ __launch_bounds__(256) void msr_qkv_reduce(
    const float* __restrict__ x, const float* __restrict__ Wq,
    const float* __restrict__ Wk, const float* __restrict__ Wv,
    float* __restrict__ outacc) {
  const int nct = V_ / TN;            // 8 channel tiles
  const int bi  = blockIdx.x;
  const int rt  = bi / nct;           // row tile (consecutive blocks share rt -> L2 reuse of x)
  const int ct  = bi % nct;
  const int r0  = rt * TM;
  const int c0  = ct * TN;

  __shared__ float Xs[BK][TM];        // k-major
  __shared__ float Ws[3][BK][TN];     // k-major, [q,k,v]
  __shared__ float red[16][TN];

  const int t  = threadIdx.x;
  const int tx = t & 15;              // channel group
  const int ty = t >> 4;              // row group

  float accq[4][4] = {{0}};
  float acck[4][4] = {{0}};
  float accv[4][4] = {{0}};

  // loader mapping: 256 threads load 64 rows x 16 k as float4
  const int lrow = t >> 2;            // 0..63
  const int lk4  = (t & 3) * 4;       // 0,4,8,12

  const float* xrow  = x  + (size_t)(r0 + lrow) * DIN;
  const float* wqrow = Wq + (size_t)(c0 + lrow) * DIN;
  const float* wkrow = Wk + (size_t)(c0 + lrow) * DIN;
  const float* wvrow = Wv + (size_t)(c0 + lrow) * DIN;

  for (int k0 = 0; k0 < DIN; k0 += BK) {
    float4 xa = *(const float4*)(xrow  + k0 + lk4);
    float4 qa = *(const float4*)(wqrow + k0 + lk4);
    float4 ka = *(const float4*)(wkrow + k0 + lk4);
    float4 va = *(const float4*)(wvrow + k0 + lk4);
    __syncthreads();  // previous iteration's reads complete
    Xs[lk4+0][lrow] = xa.x; Xs[lk4+1][lrow] = xa.y;
    Xs[lk4+2][lrow] = xa.z; Xs[lk4+3][lrow] = xa.w;
    Ws[0][lk4+0][lrow] = qa.x; Ws[0][lk4+1][lrow] = qa.y;
    Ws[0][lk4+2][lrow] = qa.z; Ws[0][lk4+3][lrow] = qa.w;
    Ws[1][lk4+0][lrow] = ka.x; Ws[1][lk4+1][lrow] = ka.y;
    Ws[1][lk4+2][lrow] = ka.z; Ws[1][lk4+3][lrow] = ka.w;
    Ws[2][lk4+0][lrow] = va.x; Ws[2][lk4+1][lrow] = va.y;
    Ws[2][lk4+2][lrow] = va.z; Ws[2][lk4+3][lrow] = va.w;
    __syncthreads();

#pragma unroll
    for (int kk = 0; kk < BK; ++kk) {
      float4 a4 = *(const float4*)&Xs[kk][ty * 4];
      float4 q4 = *(const float4*)&Ws[0][kk][tx * 4];
      float4 k4 = *(const float4*)&Ws[1][kk][tx * 4];
      float4 v4 = *(const float4*)&Ws[2][kk][tx * 4];
      float a[4]  = {a4.x, a4.y, a4.z, a4.w};
      float qw[4] = {q4.x, q4.y, q4.z, q4.w};
      float kw[4] = {k4.x, k4.y, k4.z, k4.w};
      float vw[4] = {v4.x, v4.y, v4.z, v4.w};
#pragma unroll
      for (int i = 0; i < 4; ++i) {
#pragma unroll
        for (int j = 0; j < 4; ++j) {
          accq[i][j] = fmaf(a[i], qw[j], accq[i][j]);
          acck[i][j] = fmaf(a[i], kw[j], acck[i][j]);
          accv[i][j] = fmaf(a[i], vw[j], accv[i][j]);
        }
      }
    }
  }

  // epilogue: P[i][j] = q[i][j^1]*k[i][j^1]*v[i][j]; fold rows within thread
  float pd[4];
#pragma unroll
  for (int j = 0; j < 4; ++j) {
    const int js = j ^ 1;
    float s = 0.f;
#pragma unroll
    for (int i = 0; i < 4; ++i) s += accq[i][js] * acck[i][js] * accv[i][j];
    pd[j] = s;
  }
  // fold across ty (16 row-groups). d = tx*4+j (c0 is a multiple of 64).
#pragma unroll
  for (int j = 0; j < 4; ++j) red[ty][tx * 4 + j] = pd[j];
  __syncthreads();
  if (t < 64) {
    float s = 0.f;
#pragma unroll
    for (int r = 0; r < 16; ++r) s += red[r][t];
    // (r0>>9) == b*8 + h ; entry index = b*512 + h*64 + d
    atomicAdd(&outacc[(r0 >> 9) * 64 + t], s);
  }
}

// Kernel 2: per-batch RMSNorm (with EPS) -> exact gelu -> @ Wout.T
__global__ __launch_bounds__(256) void msr_finish(
    const float* __restrict__ outacc, const float* __restrict__ gamma,
    const float* __restrict__ Wout, float* __restrict__ y) {
  const int b = blockIdx.x;
  const int t = threadIdx.x;
  __shared__ float g[V_];
  __shared__ float wsum[4];

  float v0 = outacc[b * V_ + t] * CSCALE;
  float v1 = outacc[b * V_ + 256 + t] * CSCALE;
  float ss = v0 * v0 + v1 * v1;
#pragma unroll
  for (int o = 32; o > 0; o >>= 1) ss += __shfl_down(ss, o, 64);
  if ((t & 63) == 0) wsum[t >> 6] = ss;
  __syncthreads();
  float tot = wsum[0] + wsum[1] + wsum[2] + wsum[3];
  float rs = rsqrtf(tot * (1.0f / (float)V_) + EPSF);

  float r0v = v0 * rs * gamma[t];
  float r1v = v1 * rs * gamma[t + 256];
  g[t]       = 0.5f * r0v * (1.0f + erff(r0v * 0.70710678118654752f));
  g[t + 256] = 0.5f * r1v * (1.0f + erff(r1v * 0.70710678118654752f));
  __syncthreads();

  if (t < FOUT) {
    const float* wr = Wout + (size_t)t * V_;
    float acc = 0.f;
#pragma unroll 4
    for (int c = 0; c < V_; c += 4) {
      float4 w4 = *(const float4*)(wr + c);
      acc += g[c] * w4.x + g[c + 1] * w4.y + g[c + 2] * w4.z + g[c + 3] * w4.w;
    }
    y[b * FOUT + t] = acc;
  }
}

extern "C" void kernel_launch(void* const* d_in, const int* in_sizes, int n_in,
                              void* d_out, int out_size, void* d_ws, size_t ws_size,
                              hipStream_t stream) {
  const float* x     = (const float*)d_in[0];
  const float* Wq    = (const float*)d_in[1];
  const float* Wk    = (const float*)d_in[2];
  const float* Wv    = (const float*)d_in[3];
  const float* Wout  = (const float*)d_in[4];
  const float* gamma = (const float*)d_in[5];
  float* outacc = (float*)d_ws;
  float* y = (float*)d_out;

  hipMemsetAsync(outacc, 0, B_ * V_ * sizeof(float), stream);

  const int M = B_ * S_;                      // 65536
  dim3 grid1((M / TM) * (V_ / TN));           // 1024 * 8 = 8192
  msr_qkv_reduce<<<grid1, 256, 0, stream>>>(x, Wq, Wk, Wv, outacc);
  msr_finish<<<B_, 256, 0, stream>>>(outacc, gamma, Wout, y);
}

// Round 2
// 322.711 us; speedup vs baseline: 7.7207x; 7.7207x over previous
//
#include <hip/hip_runtime.h>
#include <hip/hip_bf16.h>
#include <math.h>

#define B_   16
#define S_   4096
#define DIN  1024
#define H_   8
#define HD_  64
#define V_   512
#define FOUT 120

typedef __attribute__((ext_vector_type(8))) short bf16x8;
typedef __attribute__((ext_vector_type(4))) float f32x4;

#define AS1 __attribute__((address_space(1)))
#define AS3 __attribute__((address_space(3)))

__device__ const float CSCALE = 0.1f / (64.0f * 4096.0f);
__device__ const float EPSF = 1e-5f;

__device__ inline void gl2lds16(const void* g, void* l) {
  __builtin_amdgcn_global_load_lds((const AS1 unsigned int*)g,
                                   (AS3 unsigned int*)l, 16, 0, 0);
}

// fp32 -> bf16 RNE (no NaN handling; inputs are finite)
__device__ inline unsigned short f2b(float f) {
  unsigned u = __builtin_bit_cast(unsigned, f);
  unsigned r = (u + 0x7FFFu + ((u >> 16) & 1u)) >> 16;
  return (unsigned short)r;
}

__device__ inline bf16x8 pack8(float4 a, float4 b) {
  bf16x8 r;
  r[0] = (short)f2b(a.x); r[1] = (short)f2b(a.y);
  r[2] = (short)f2b(a.z); r[3] = (short)f2b(a.w);
  r[4] = (short)f2b(b.x); r[5] = (short)f2b(b.y);
  r[6] = (short)f2b(b.z); r[7] = (short)f2b(b.w);
  return r;
}

#define IMG 24576  // shorts per (ct,k0) weight image = 48KB

// Pre-kernel: convert Wq/Wk/Wv fp32 -> bf16, fragment-major tile layout.
// unit u = ((((ct*16 + k0)*3 + g)*8 + ns)*2 + ks2)*64 + lane ; 8 bf16 per unit.
__global__ void msr_convw(const float* __restrict__ Wq, const float* __restrict__ Wk,
                          const float* __restrict__ Wv, unsigned short* __restrict__ Wt) {
  int u = blockIdx.x * 256 + threadIdx.x;        // 0..196607
  int lane = u & 63;
  int ks2 = (u >> 6) & 1;
  int ns  = (u >> 7) & 7;
  int idx3 = u >> 10;                            // (ct*16+k0)*3 + g
  int g = idx3 % 3;
  int rest = idx3 / 3;
  int k0 = rest & 15;
  int ct = rest >> 4;
  const float* W = (g == 0) ? Wq : (g == 1) ? Wk : Wv;
  int row = ct * 128 + ns * 16 + (lane & 15);
  int kb  = k0 * 64 + ks2 * 32 + (lane >> 4) * 8;
  const float* src = W + (size_t)row * DIN + kb;
  float4 a = *(const float4*)src;
  float4 b = *(const float4*)(src + 4);
  *(bf16x8*)(Wt + (size_t)u * 8) = pack8(a, b);
}

// Main: fused q/k/v bf16 MFMA GEMM + pair-swap triple product + fold.
// Block: 256 thr = 4 waves; tile 64(M) x 128(N); BK=64; wave tile 64x32.
__global__ __launch_bounds__(256, 2) void msr_main(
    const float* __restrict__ x, const unsigned short* __restrict__ Wt,
    float* __restrict__ outacc) {
  int bid = blockIdx.x;
  int swz = (bid & 7) * 512 + (bid >> 3);   // XCD swizzle (4096 % 8 == 0)
  int ct = swz >> 10;                       // 0..3
  int rt = swz & 1023;                      // 0..1023
  int r0 = rt * 64;

  __shared__ __align__(16) unsigned short As[64 * 64];        // 8 KB, frag-major
  __shared__ __align__(16) unsigned short Bs[3 * 128 * 64];   // 48 KB, frag-major
  __shared__ float red[4][32];

  int t = threadIdx.x;
  int w = t >> 6, lane = t & 63;

  f32x4 acc[3][4][2];
#pragma unroll
  for (int g = 0; g < 3; ++g)
#pragma unroll
    for (int m = 0; m < 4; ++m)
#pragma unroll
      for (int n = 0; n < 2; ++n) acc[g][m][n] = (f32x4){0.f, 0.f, 0.f, 0.f};

  // A staging: unit u0=t (rows 0..31), u1=t+256 (rows 32..63); row=u>>3, kg=u&7
  int row0 = t >> 3, kg0 = t & 7;
  int row1 = row0 + 32;
  const float* xp0 = x + (size_t)(r0 + row0) * DIN + kg0 * 8;
  const float* xp1 = x + (size_t)(r0 + row1) * DIN + kg0 * 8;
  int au0 = ((((row0 >> 4) * 2 + (kg0 >> 2)) * 64) + (kg0 & 3) * 16 + (row0 & 15)) * 8;
  int au1 = ((((row1 >> 4) * 2 + (kg0 >> 2)) * 64) + (kg0 & 3) * 16 + (row1 & 15)) * 8;

  const unsigned short* wimg = Wt + (size_t)ct * 16 * IMG;

  for (int k0 = 0; k0 < 16; ++k0) {
    const float* p0 = xp0 + k0 * 64;
    float4 xa = *(const float4*)p0;
    float4 xb = *(const float4*)(p0 + 4);
    const float* p1 = xp1 + k0 * 64;
    float4 xc = *(const float4*)p1;
    float4 xd = *(const float4*)(p1 + 4);

    __syncthreads();  // previous compute done reading LDS

    const unsigned short* wsrc = wimg + (size_t)k0 * IMG;
#pragma unroll
    for (int i = 0; i < 12; ++i) {
      int chunk = w * 12 + i;
      gl2lds16(wsrc + (size_t)chunk * 512 + lane * 8, (char*)Bs + chunk * 1024);
    }
    *(bf16x8*)(As + au0) = pack8(xa, xb);
    *(bf16x8*)(As + au1) = pack8(xc, xd);

    __syncthreads();  // drains vmcnt (B loads) + lgkm (A writes)

#pragma unroll
    for (int ks2 = 0; ks2 < 2; ++ks2) {
      bf16x8 afr[4];
#pragma unroll
      for (int m = 0; m < 4; ++m)
        afr[m] = *(const bf16x8*)(As + ((m * 2 + ks2) * 64 + lane) * 8);
#pragma unroll
      for (int g = 0; g < 3; ++g) {
        int nsb = w * 2;
        bf16x8 b0 = *(const bf16x8*)(Bs + (((g * 8 + nsb) * 2 + ks2) * 64 + lane) * 8);
        bf16x8 b1 = *(const bf16x8*)(Bs + (((g * 8 + nsb + 1) * 2 + ks2) * 64 + lane) * 8);
#pragma unroll
        for (int m = 0; m < 4; ++m) {
          acc[g][m][0] = __builtin_amdgcn_mfma_f32_16x16x32_bf16(afr[m], b0, acc[g][m][0], 0, 0, 0);
          acc[g][m][1] = __builtin_amdgcn_mfma_f32_16x16x32_bf16(afr[m], b1, acc[g][m][1], 0, 0, 0);
        }
      }
    }
  }

  // Epilogue: p = (q*k)[c^1] * v[c]; C/D layout col=lane&15, row=(lane>>4)*4+reg
  float pd0 = 0.f, pd1 = 0.f;
#pragma unroll
  for (int m = 0; m < 4; ++m)
#pragma unroll
    for (int r = 0; r < 4; ++r) {
      float qk0 = acc[0][m][0][r] * acc[1][m][0][r];
      float qk1 = acc[0][m][1][r] * acc[1][m][1][r];
      pd0 += __shfl_xor(qk0, 1, 64) * acc[2][m][0][r];
      pd1 += __shfl_xor(qk1, 1, 64) * acc[2][m][1][r];
    }
  // fold rows across lane groups (rows = (lane>>4)*4 + r, msub covered in-thread)
  pd0 += __shfl_xor(pd0, 16, 64); pd0 += __shfl_xor(pd0, 32, 64);
  pd1 += __shfl_xor(pd1, 16, 64); pd1 += __shfl_xor(pd1, 32, 64);

  if (lane < 16) { red[w][lane] = pd0; red[w][16 + lane] = pd1; }
  __syncthreads();
  if (t < 64) {
    int half = t >> 5, idx = t & 31;      // wave w covers d-range (w&1)*32..+32
    float s = red[half][idx] + red[half + 2][idx];
    atomicAdd(&outacc[((r0 >> 9) << 6) + t], s);
  }
}

// Finish: per-batch RMSNorm -> exact gelu -> @ Wout.T  (unchanged, verified)
__global__ __launch_bounds__(256) void msr_finish(
    const float* __restrict__ outacc, const float* __restrict__ gamma,
    const float* __restrict__ Wout, float* __restrict__ y) {
  const int b = blockIdx.x;
  const int t = threadIdx.x;
  __shared__ float g[V_];
  __shared__ float wsum[4];

  float v0 = outacc[b * V_ + t] * CSCALE;
  float v1 = outacc[b * V_ + 256 + t] * CSCALE;
  float ss = v0 * v0 + v1 * v1;
#pragma unroll
  for (int o = 32; o > 0; o >>= 1) ss += __shfl_down(ss, o, 64);
  if ((t & 63) == 0) wsum[t >> 6] = ss;
  __syncthreads();
  float tot = wsum[0] + wsum[1] + wsum[2] + wsum[3];
  float rs = rsqrtf(tot * (1.0f / (float)V_) + EPSF);

  float r0v = v0 * rs * gamma[t];
  float r1v = v1 * rs * gamma[t + 256];
  g[t]       = 0.5f * r0v * (1.0f + erff(r0v * 0.70710678118654752f));
  g[t + 256] = 0.5f * r1v * (1.0f + erff(r1v * 0.70710678118654752f));
  __syncthreads();

  if (t < FOUT) {
    const float* wr = Wout + (size_t)t * V_;
    float acc = 0.f;
#pragma unroll 4
    for (int c = 0; c < V_; c += 4) {
      float4 w4 = *(const float4*)(wr + c);
      acc += g[c] * w4.x + g[c + 1] * w4.y + g[c + 2] * w4.z + g[c + 3] * w4.w;
    }
    y[b * FOUT + t] = acc;
  }
}

extern "C" void kernel_launch(void* const* d_in, const int* in_sizes, int n_in,
                              void* d_out, int out_size, void* d_ws, size_t ws_size,
                              hipStream_t stream) {
  const float* x     = (const float*)d_in[0];
  const float* Wq    = (const float*)d_in[1];
  const float* Wk    = (const float*)d_in[2];
  const float* Wv    = (const float*)d_in[3];
  const float* Wout  = (const float*)d_in[4];
  const float* gamma = (const float*)d_in[5];

  float* outacc = (float*)d_ws;                                  // 32 KB
  unsigned short* Wt = (unsigned short*)((char*)d_ws + 32768);   // 3 MB bf16 weights
  float* y = (float*)d_out;

  msr_convw<<<768, 256, 0, stream>>>(Wq, Wk, Wv, Wt);
  hipMemsetAsync(outacc, 0, B_ * V_ * sizeof(float), stream);
  msr_main<<<4096, 256, 0, stream>>>(x, Wt, outacc);
  msr_finish<<<B_, 256, 0, stream>>>(outacc, gamma, Wout, y);
}

// Round 3
// 318.929 us; speedup vs baseline: 7.8123x; 1.0119x over previous
//
#include <hip/hip_runtime.h>
#include <hip/hip_bf16.h>
#include <math.h>

#define B_   16
#define S_   4096
#define DIN  1024
#define V_   512
#define FOUT 120

typedef __attribute__((ext_vector_type(8))) short bf16x8;
typedef __attribute__((ext_vector_type(4))) float f32x4;

#define AS1 __attribute__((address_space(1)))
#define AS3 __attribute__((address_space(3)))

__device__ const float CSCALE = 0.1f / (64.0f * 4096.0f);
__device__ const float EPSF = 1e-5f;

__device__ inline void gl2lds16(const void* g, void* l) {
  __builtin_amdgcn_global_load_lds((const AS1 unsigned int*)g,
                                   (AS3 unsigned int*)l, 16, 0, 0);
}

// fp32 -> bf16 RNE
__device__ inline unsigned short f2b(float f) {
  unsigned u = __builtin_bit_cast(unsigned, f);
  unsigned r = (u + 0x7FFFu + ((u >> 16) & 1u)) >> 16;
  return (unsigned short)r;
}

__device__ inline bf16x8 pack8(float4 a, float4 b) {
  bf16x8 r;
  r[0] = (short)f2b(a.x); r[1] = (short)f2b(a.y);
  r[2] = (short)f2b(a.z); r[3] = (short)f2b(a.w);
  r[4] = (short)f2b(b.x); r[5] = (short)f2b(b.y);
  r[6] = (short)f2b(b.z); r[7] = (short)f2b(b.w);
  return r;
}

// Wt layout: unit uu = ((ct*32 + k0)*3 + g)*8 + ns ; per unit 64 lanes x 8 bf16.
// lane l: row = ct*128 + ns*16 + (l&15), k = k0*32 + (l>>4)*8 .. +8
// IMG per (ct,k0) = 24 units * 512 shorts = 12288 shorts = 24KB.
__global__ void msr_convw(const float* __restrict__ Wq, const float* __restrict__ Wk,
                          const float* __restrict__ Wv, unsigned short* __restrict__ Wt) {
  int u = blockIdx.x * 256 + threadIdx.x;   // 0..196607
  int lane = u & 63;
  int uu = u >> 6;                          // 0..3071
  int ns = uu & 7;
  int g3 = (uu >> 3) % 3;
  int kk = (uu >> 3) / 3;                   // ct*32 + k0
  int k0 = kk & 31;
  int ct = kk >> 5;
  const float* W = (g3 == 0) ? Wq : (g3 == 1) ? Wk : Wv;
  int row = ct * 128 + ns * 16 + (lane & 15);
  int kb  = k0 * 32 + (lane >> 4) * 8;
  const float* src = W + (size_t)row * DIN + kb;
  float4 a = *(const float4*)src;
  float4 b = *(const float4*)(src + 4);
  *(bf16x8*)(Wt + (size_t)u * 8) = pack8(a, b);
}

#define WAITVM0 asm volatile("s_waitcnt vmcnt(0)" ::: "memory")
#define WAITVM2 asm volatile("s_waitcnt vmcnt(2)" ::: "memory")
#define WAITVM3 asm volatile("s_waitcnt vmcnt(3)" ::: "memory")
#define WAITLGKM asm volatile("s_waitcnt lgkmcnt(0)" ::: "memory")
#define SCHEDB __builtin_amdgcn_sched_barrier(0)

__device__ inline void wg_barrier() {
  asm volatile("" ::: "memory");
  __builtin_amdgcn_s_barrier();
  asm volatile("" ::: "memory");
}

// Main: M=128 x-tile, N=128 channels x 3 gemms, BK=32, double-buffered,
// counted-vmcnt pipeline, 8 waves (2M x 4N).
__global__ __launch_bounds__(512, 2) void msr_main(
    const float* __restrict__ x, const unsigned short* __restrict__ Wt,
    float* __restrict__ outacc) {
  int bid = blockIdx.x;
  int swz = (bid & 7) * 256 + (bid >> 3);   // XCD swizzle, 2048 % 8 == 0
  int ct = swz >> 9;                        // 0..3
  int rt = swz & 511;                       // 0..511
  int r0 = rt << 7;

  __shared__ __align__(16) unsigned short As[2][4096];    // 2 x 8KB
  __shared__ __align__(16) unsigned short Bs[2][12288];   // 2 x 24KB

  const int t = threadIdx.x;
  const int w = t >> 6, lane = t & 63;
  const int wm4 = (w >> 2) * 4;     // m-frag base (0 or 4)
  const int nf0 = (w & 3) * 2;      // n-frag base (0,2,4,6)
  const int w3 = w * 3;
  const int ctk32 = ct * 32;

  // A loader: thread t -> row = t>>2 (0..127), kg = t&3 (k-octet)
  // dest unit = w (wave-uniform), lane' = (t&3)*16 + ((t>>2)&15)  [bijective/wave]
  const int awoff = (w * 64 + (t & 3) * 16 + ((t >> 2) & 15)) * 8;
  const float* xbase = x + (size_t)(r0 + (t >> 2)) * DIN + (t & 3) * 8;

  f32x4 acc[3][4][2];
#pragma unroll
  for (int g = 0; g < 3; ++g)
#pragma unroll
    for (int m = 0; m < 4; ++m)
#pragma unroll
      for (int n = 0; n < 2; ++n) acc[g][m][n] = (f32x4){0.f, 0.f, 0.f, 0.f};

  float4 xr0, xr1;

#define LOADX(kn) { const float* p = xbase + (kn) * 32; \
  asm volatile("global_load_dwordx4 %0, %1, off" : "=v"(xr0) : "v"(p) : "memory"); \
  asm volatile("global_load_dwordx4 %0, %1, off offset:16" : "=v"(xr1) : "v"(p) : "memory"); }

#define WRITEA(cb) { *(bf16x8*)(&As[cb][awoff]) = pack8(xr0, xr1); }

#define STAGEB(kn, cb) { \
  const unsigned short* wp = Wt + (size_t)(ctk32 + (kn)) * 12288 + w3 * 512 + lane * 8; \
  unsigned short* lp = &Bs[cb][w3 * 512]; \
  gl2lds16(wp, lp); \
  gl2lds16(wp + 512, lp + 512); \
  gl2lds16(wp + 1024, lp + 1024); }

#define PHASE(c) { \
  const unsigned short* Ab = &As[c][0]; \
  const unsigned short* Bb = &Bs[c][0]; \
  bf16x8 afr[4]; bf16x8 bfr[3][2]; \
  _Pragma("unroll") for (int m = 0; m < 4; ++m) \
    afr[m] = *(const bf16x8*)(Ab + ((wm4 + m) * 64 + lane) * 8); \
  _Pragma("unroll") for (int g = 0; g < 3; ++g) \
    _Pragma("unroll") for (int n = 0; n < 2; ++n) \
      bfr[g][n] = *(const bf16x8*)(Bb + ((g * 8 + nf0 + n) * 64 + lane) * 8); \
  __builtin_amdgcn_s_setprio(1); \
  _Pragma("unroll") for (int g = 0; g < 3; ++g) \
    _Pragma("unroll") for (int m = 0; m < 4; ++m) \
      _Pragma("unroll") for (int n = 0; n < 2; ++n) \
        acc[g][m][n] = __builtin_amdgcn_mfma_f32_16x16x32_bf16(afr[m], bfr[g][n], acc[g][m][n], 0, 0, 0); \
  __builtin_amdgcn_s_setprio(0); \
}

#define ITERF(kn, c) { \
  PHASE(c); \
  WAITVM3; SCHEDB; \
  WRITEA((c) ^ 1); \
  LOADX((kn) + 2); \
  WAITVM2; WAITLGKM; \
  wg_barrier(); \
  STAGEB((kn) + 2, c); }

  // ---- prologue ----
  LOADX(0);
  WAITVM0; SCHEDB;
  WRITEA(0);
  STAGEB(0, 0);
  LOADX(1);
  WAITVM2; WAITLGKM;
  wg_barrier();
  STAGEB(1, 1);
  // in-flight: X(1) [2, older], B(1) [3, newer]

  // ---- main loop: k0 = 0..29 ----
#pragma unroll 1
  for (int i = 0; i < 15; ++i) {
    const int k0 = i * 2;
    ITERF(k0, 0);
    ITERF(k0 + 1, 1);
  }
  // ---- iter 30 ----
  PHASE(0);
  WAITVM3; SCHEDB;
  WRITEA(1);
  WAITVM0; WAITLGKM;
  wg_barrier();
  // ---- iter 31 ----
  PHASE(1);

  // ---- epilogue: p = (q*k)[c^1] * v[c], fold rows, block-reduce ----
  float pd0 = 0.f, pd1 = 0.f;
#pragma unroll
  for (int m = 0; m < 4; ++m)
#pragma unroll
    for (int r = 0; r < 4; ++r) {
      float qk0 = acc[0][m][0][r] * acc[1][m][0][r];
      float qk1 = acc[0][m][1][r] * acc[1][m][1][r];
      pd0 += __shfl_xor(qk0, 1, 64) * acc[2][m][0][r];
      pd1 += __shfl_xor(qk1, 1, 64) * acc[2][m][1][r];
    }
  pd0 += __shfl_xor(pd0, 16, 64); pd0 += __shfl_xor(pd0, 32, 64);
  pd1 += __shfl_xor(pd1, 16, 64); pd1 += __shfl_xor(pd1, 32, 64);

  float* red = (float*)&As[0][0];   // As[0] no longer read
  if (lane < 16) { red[w * 32 + lane] = pd0; red[w * 32 + 16 + lane] = pd1; }
  __syncthreads();
  if (t < 64) {
    int wn0 = t >> 5, idx = t & 31;
    float s = red[wn0 * 32 + idx] + red[(wn0 + 2) * 32 + idx] +
              red[(wn0 + 4) * 32 + idx] + red[(wn0 + 6) * 32 + idx];
    atomicAdd(&outacc[((rt >> 2) << 6) + t], s);
  }
#undef LOADX
#undef WRITEA
#undef STAGEB
#undef PHASE
#undef ITERF
}

// Finish: per-batch RMSNorm -> exact gelu -> @ Wout.T
__global__ __launch_bounds__(256) void msr_finish(
    const float* __restrict__ outacc, const float* __restrict__ gamma,
    const float* __restrict__ Wout, float* __restrict__ y) {
  const int b = blockIdx.x;
  const int t = threadIdx.x;
  __shared__ float g[V_];
  __shared__ float wsum[4];

  float v0 = outacc[b * V_ + t] * CSCALE;
  float v1 = outacc[b * V_ + 256 + t] * CSCALE;
  float ss = v0 * v0 + v1 * v1;
#pragma unroll
  for (int o = 32; o > 0; o >>= 1) ss += __shfl_down(ss, o, 64);
  if ((t & 63) == 0) wsum[t >> 6] = ss;
  __syncthreads();
  float tot = wsum[0] + wsum[1] + wsum[2] + wsum[3];
  float rs = rsqrtf(tot * (1.0f / (float)V_) + EPSF);

  float r0v = v0 * rs * gamma[t];
  float r1v = v1 * rs * gamma[t + 256];
  g[t]       = 0.5f * r0v * (1.0f + erff(r0v * 0.70710678118654752f));
  g[t + 256] = 0.5f * r1v * (1.0f + erff(r1v * 0.70710678118654752f));
  __syncthreads();

  if (t < FOUT) {
    const float* wr = Wout + (size_t)t * V_;
    float acc = 0.f;
#pragma unroll 4
    for (int c = 0; c < V_; c += 4) {
      float4 w4 = *(const float4*)(wr + c);
      acc += g[c] * w4.x + g[c + 1] * w4.y + g[c + 2] * w4.z + g[c + 3] * w4.w;
    }
    y[b * FOUT + t] = acc;
  }
}

extern "C" void kernel_launch(void* const* d_in, const int* in_sizes, int n_in,
                              void* d_out, int out_size, void* d_ws, size_t ws_size,
                              hipStream_t stream) {
  const float* x     = (const float*)d_in[0];
  const float* Wq    = (const float*)d_in[1];
  const float* Wk    = (const float*)d_in[2];
  const float* Wv    = (const float*)d_in[3];
  const float* Wout  = (const float*)d_in[4];
  const float* gamma = (const float*)d_in[5];

  float* outacc = (float*)d_ws;                                  // 32 KB
  unsigned short* Wt = (unsigned short*)((char*)d_ws + 32768);   // 3 MB bf16 weights
  float* y = (float*)d_out;

  msr_convw<<<768, 256, 0, stream>>>(Wq, Wk, Wv, Wt);
  hipMemsetAsync(outacc, 0, B_ * V_ * sizeof(float), stream);
  msr_main<<<2048, 512, 0, stream>>>(x, Wt, outacc);
  msr_finish<<<B_, 256, 0, stream>>>(outacc, gamma, Wout, y);
}